// Round 4
// baseline (296.578 us; speedup 1.0000x reference)
//
#include <hip/hip_runtime.h>
#include <cstdint>

#define NTOT 4096   // 2b rows
#define BHALF 2048  // b
#define D1 4096
#define D2 2048
#define TT 32       // 4096/128 tiles per dim
#define NTILES 528  // TT*(TT+1)/2

typedef __attribute__((ext_vector_type(4))) float f32x4;
typedef __attribute__((ext_vector_type(4))) int i32x4;
typedef __attribute__((ext_vector_type(8))) int i32x8;

// async 16B global->LDS DMA (wave-uniform LDS base + lane*16 scatter)
__device__ __forceinline__ void glds16(const uint8_t* g, uint8_t* l) {
    __builtin_amdgcn_global_load_lds(
        (const __attribute__((address_space(1))) void*)(uintptr_t)g,
        (__attribute__((address_space(3))) void*)(uint32_t)(uintptr_t)l,
        16, 0, 0);
}

// raw LDS b128 read, opaque to the compiler's waitcnt insertion
__device__ __forceinline__ i32x4 ldsr(uint32_t addr) {
    i32x4 r;
    asm volatile("ds_read_b128 %0, %1" : "=v"(r) : "v"(addr));
    return r;
}

// e4m3fn decode (for colsum only; data never near NaN/448)
__device__ __forceinline__ float fp8dec(unsigned b) {
    unsigned e = (b >> 3) & 15u, m = b & 7u;
    float v = e ? __uint_as_float(((e + 120u) << 23) | (m << 20))
                : (float)m * 0.001953125f;   // subnormal: m * 2^-9
    return (b & 128u) ? -v : v;
}

// ---------------- prep: per-row sumsq (fp32) + fp8 e4m3 convert ----------------
// Round-0 validated 8192-block form. Bit-exact per-thread accumulation order.
// R4 additions: block 2 zeroes the jmmd control words and stores the loss bias
// (both every iteration -> robust to harness reset behavior and rocprof replay).
__global__ void prep_kernel(const float* __restrict__ z1s, const float* __restrict__ z1t,
                            const float* __restrict__ z2s, const float* __restrict__ z2t,
                            float* __restrict__ sq1, float* __restrict__ sq2,
                            uint8_t* __restrict__ t1f8, uint8_t* __restrict__ t2f8,
                            float* __restrict__ s1, float* __restrict__ s2,
                            unsigned* __restrict__ ctrl, float* __restrict__ out) {
    int bid = blockIdx.x;
    int tid = threadIdx.x;
    if (bid == 0) { for (int i = tid; i < 4096; i += 256) s1[i] = 0.f; }
    if (bid == 1) { for (int i = tid; i < 2048; i += 256) s2[i] = 0.f; }
    if (bid == 2) {
        if (tid < 4) ctrl[tid] = 0u;                    // done ctr, flag, c1 bits, c2 bits
        if (tid == 4) out[0] = 2.0f / (float)(BHALF - 1);
    }
    int which = bid >> 12;
    int row = bid & 4095;
    int d = which ? D2 : D1;
    const float* s_ = which ? z2s : z1s;
    const float* t_ = which ? z2t : z1t;
    const float* src = (row < BHALF) ? s_ + (size_t)row * d : t_ + (size_t)(row - BHALF) * d;
    uint8_t* dst = (which ? t2f8 : t1f8) + (size_t)row * d;
    float* sq = which ? sq2 : sq1;
    const float4* src4 = (const float4*)src;
    float a = 0.f;
    int n8 = d >> 3;
    for (int i = tid; i < n8; i += 256) {
        float4 v0 = src4[2 * i], v1 = src4[2 * i + 1];
        a += v0.x * v0.x + v0.y * v0.y + v0.z * v0.z + v0.w * v0.w;
        a += v1.x * v1.x + v1.y * v1.y + v1.z * v1.z + v1.w * v1.w;
        int w0 = __builtin_amdgcn_cvt_pk_fp8_f32(v0.x, v0.y, 0, 0);
        w0 = __builtin_amdgcn_cvt_pk_fp8_f32(v0.z, v0.w, w0, 1);
        int w1 = __builtin_amdgcn_cvt_pk_fp8_f32(v1.x, v1.y, 0, 0);
        w1 = __builtin_amdgcn_cvt_pk_fp8_f32(v1.z, v1.w, w1, 1);
        ((uint2*)dst)[i] = uint2{(unsigned)w0, (unsigned)w1};
    }
    for (int o = 32; o; o >>= 1) a += __shfl_down(a, o);
    __shared__ float sh[4];
    int lane = tid & 63, w = tid >> 6;
    if (lane == 0) sh[w] = a;
    __syncthreads();
    if (tid == 0) sq[row] = sh[0] + sh[1] + sh[2] + sh[3];
}

// ---------------- pipelined MX-fp8 GEMM K-loop (R2-validated 4-wave form) ----------
// Double-buffered LDS; prefetch issued BEFORE the barrier; counted vmcnt(8);
// frag reads via opaque asm ds_read_b128 with counted lgkmcnt(8)/(4)/(0);
// WAR barrier after lgkmcnt(0) so the final 8 MFMAs run in the barrier shadow.
// XOR chunk swizzle: logical 16B chunk c of row r at slot c^(r&7).
__device__ __forceinline__ void gemm_mx_pipe(const uint8_t* __restrict__ ga,
                                             const uint8_t* __restrict__ gb,
                                             int d,
                                             uint8_t* A0, uint8_t* B0,
                                             uint8_t* A1, uint8_t* B1,
                                             f32x4 (&acc)[4][4], int wv, int lane,
                                             int wm, int wn, int lm, int quad) {
    int nsteps = d >> 7;
    int rsub = lane >> 3;
    int ql = (lane & 7) ^ rsub;          // swizzled source chunk
    const uint8_t* pa = ga + (size_t)(wv * 32 + rsub) * d + ql * 16;
    const uint8_t* pb = gb + (size_t)(wv * 32 + rsub) * d + ql * 16;
    uint8_t* dA[2] = { A0 + wv * 4096, A1 + wv * 4096 };
    uint8_t* dB[2] = { B0 + wv * 4096, B1 + wv * 4096 };
    uint32_t baseA[2] = { (uint32_t)(uintptr_t)A0, (uint32_t)(uintptr_t)A1 };
    uint32_t baseB[2] = { (uint32_t)(uintptr_t)B0, (uint32_t)(uintptr_t)B1 };
    int s0 = ((2 * quad) ^ (lm & 7)) * 16;
    int s1 = ((2 * quad + 1) ^ (lm & 7)) * 16;
    uint32_t offA[4], offB[4];
#pragma unroll
    for (int i = 0; i < 4; ++i) {
        offA[i] = (uint32_t)((wm * 64 + i * 16 + lm) * 128);
        offB[i] = (uint32_t)((wn * 64 + i * 16 + lm) * 128);
    }
    // prime buffer 0 (k=0)
#pragma unroll
    for (int i = 0; i < 4; ++i) {
        glds16(pa + (size_t)i * 8 * d, dA[0] + i * 1024);
        glds16(pb + (size_t)i * 8 * d, dB[0] + i * 1024);
    }
    for (int k = 0; k < nsteps; ++k) {
        int cur = k & 1, nxt = cur ^ 1;
        size_t koff = (size_t)((k + 1 < nsteps) ? (k + 1) : 0) << 7;
#pragma unroll
        for (int i = 0; i < 4; ++i) {
            glds16(pa + koff + (size_t)i * 8 * d, dA[nxt] + i * 1024);
            glds16(pb + koff + (size_t)i * 8 * d, dB[nxt] + i * 1024);
        }
        asm volatile("s_waitcnt vmcnt(8)\n\ts_barrier" ::: "memory");
        i32x4 b00 = ldsr(baseB[cur] + offB[0] + s0), b01 = ldsr(baseB[cur] + offB[0] + s1);
        i32x4 b10 = ldsr(baseB[cur] + offB[1] + s0), b11 = ldsr(baseB[cur] + offB[1] + s1);
        i32x4 a00 = ldsr(baseA[cur] + offA[0] + s0), a01 = ldsr(baseA[cur] + offA[0] + s1);
        i32x4 a10 = ldsr(baseA[cur] + offA[1] + s0), a11 = ldsr(baseA[cur] + offA[1] + s1);
        i32x4 b20 = ldsr(baseB[cur] + offB[2] + s0), b21 = ldsr(baseB[cur] + offB[2] + s1);
        i32x4 b30 = ldsr(baseB[cur] + offB[3] + s0), b31 = ldsr(baseB[cur] + offB[3] + s1);
        i32x4 a20 = ldsr(baseA[cur] + offA[2] + s0), a21 = ldsr(baseA[cur] + offA[2] + s1);
        i32x4 a30 = ldsr(baseA[cur] + offA[3] + s0), a31 = ldsr(baseA[cur] + offA[3] + s1);
        union F { i32x4 h[2]; i32x8 v; };
        F ua0, ua1, ua2, ua3, ub0, ub1, ub2, ub3;
        // ---- cluster 0: needs first 8 reads (8 in flight) ----
        asm volatile("s_waitcnt lgkmcnt(8)"
                     : "+v"(b00), "+v"(b01), "+v"(b10), "+v"(b11),
                       "+v"(a00), "+v"(a01), "+v"(a10), "+v"(a11));
        __builtin_amdgcn_sched_barrier(0);
        ub0.h[0] = b00; ub0.h[1] = b01; ub1.h[0] = b10; ub1.h[1] = b11;
        ua0.h[0] = a00; ua0.h[1] = a01; ua1.h[0] = a10; ua1.h[1] = a11;
        __builtin_amdgcn_s_setprio(1);
        acc[0][0] = __builtin_amdgcn_mfma_scale_f32_16x16x128_f8f6f4(ua0.v, ub0.v, acc[0][0], 0, 0, 0, 0x7F7F7F7F, 0, 0x7F7F7F7F);
        acc[0][1] = __builtin_amdgcn_mfma_scale_f32_16x16x128_f8f6f4(ua0.v, ub1.v, acc[0][1], 0, 0, 0, 0x7F7F7F7F, 0, 0x7F7F7F7F);
        acc[1][0] = __builtin_amdgcn_mfma_scale_f32_16x16x128_f8f6f4(ua1.v, ub0.v, acc[1][0], 0, 0, 0, 0x7F7F7F7F, 0, 0x7F7F7F7F);
        acc[1][1] = __builtin_amdgcn_mfma_scale_f32_16x16x128_f8f6f4(ua1.v, ub1.v, acc[1][1], 0, 0, 0, 0x7F7F7F7F, 0, 0x7F7F7F7F);
        __builtin_amdgcn_s_setprio(0);
        // ---- cluster 1: + B frag 2,3 ----
        asm volatile("s_waitcnt lgkmcnt(4)"
                     : "+v"(b20), "+v"(b21), "+v"(b30), "+v"(b31));
        __builtin_amdgcn_sched_barrier(0);
        ub2.h[0] = b20; ub2.h[1] = b21; ub3.h[0] = b30; ub3.h[1] = b31;
        __builtin_amdgcn_s_setprio(1);
        acc[0][2] = __builtin_amdgcn_mfma_scale_f32_16x16x128_f8f6f4(ua0.v, ub2.v, acc[0][2], 0, 0, 0, 0x7F7F7F7F, 0, 0x7F7F7F7F);
        acc[0][3] = __builtin_amdgcn_mfma_scale_f32_16x16x128_f8f6f4(ua0.v, ub3.v, acc[0][3], 0, 0, 0, 0x7F7F7F7F, 0, 0x7F7F7F7F);
        acc[1][2] = __builtin_amdgcn_mfma_scale_f32_16x16x128_f8f6f4(ua1.v, ub2.v, acc[1][2], 0, 0, 0, 0x7F7F7F7F, 0, 0x7F7F7F7F);
        acc[1][3] = __builtin_amdgcn_mfma_scale_f32_16x16x128_f8f6f4(ua1.v, ub3.v, acc[1][3], 0, 0, 0, 0x7F7F7F7F, 0, 0x7F7F7F7F);
        __builtin_amdgcn_s_setprio(0);
        // ---- all reads landed: release buffer (WAR barrier); clusters 2/3 run
        // register-only in the barrier shadow ----
        asm volatile("s_waitcnt lgkmcnt(0)"
                     : "+v"(a20), "+v"(a21), "+v"(a30), "+v"(a31));
        __builtin_amdgcn_sched_barrier(0);
        asm volatile("s_barrier" ::: "memory");
        __builtin_amdgcn_sched_barrier(0);
        ua2.h[0] = a20; ua2.h[1] = a21; ua3.h[0] = a30; ua3.h[1] = a31;
        __builtin_amdgcn_s_setprio(1);
        acc[2][0] = __builtin_amdgcn_mfma_scale_f32_16x16x128_f8f6f4(ua2.v, ub0.v, acc[2][0], 0, 0, 0, 0x7F7F7F7F, 0, 0x7F7F7F7F);
        acc[2][1] = __builtin_amdgcn_mfma_scale_f32_16x16x128_f8f6f4(ua2.v, ub1.v, acc[2][1], 0, 0, 0, 0x7F7F7F7F, 0, 0x7F7F7F7F);
        acc[2][2] = __builtin_amdgcn_mfma_scale_f32_16x16x128_f8f6f4(ua2.v, ub2.v, acc[2][2], 0, 0, 0, 0x7F7F7F7F, 0, 0x7F7F7F7F);
        acc[2][3] = __builtin_amdgcn_mfma_scale_f32_16x16x128_f8f6f4(ua2.v, ub3.v, acc[2][3], 0, 0, 0, 0x7F7F7F7F, 0, 0x7F7F7F7F);
        acc[3][0] = __builtin_amdgcn_mfma_scale_f32_16x16x128_f8f6f4(ua3.v, ub0.v, acc[3][0], 0, 0, 0, 0x7F7F7F7F, 0, 0x7F7F7F7F);
        acc[3][1] = __builtin_amdgcn_mfma_scale_f32_16x16x128_f8f6f4(ua3.v, ub1.v, acc[3][1], 0, 0, 0, 0x7F7F7F7F, 0, 0x7F7F7F7F);
        acc[3][2] = __builtin_amdgcn_mfma_scale_f32_16x16x128_f8f6f4(ua3.v, ub2.v, acc[3][2], 0, 0, 0, 0x7F7F7F7F, 0, 0x7F7F7F7F);
        acc[3][3] = __builtin_amdgcn_mfma_scale_f32_16x16x128_f8f6f4(ua3.v, ub3.v, acc[3][3], 0, 0, 0, 0x7F7F7F7F, 0, 0x7F7F7F7F);
        __builtin_amdgcn_s_setprio(0);
    }
}

// ---------------- fused: colsum stripes + dynamic finalize + dual-GEMM + epilogue ----
// R4: colsum_fp8_kernel and finalize_kernel dispatches are FOLDED IN, overlapped
// under the GEMM phase. Blocks 0..383 run the identical colsum stripe first
// (same mapping/partials/atomic targets). The 384th completer runs finalize
// (identical math; s1/s2 read via bit-exact atomicOr loads — device-scope, since
// normal loads could hit a stale XCD-local L2 copy of prep's zeros), publishes
// c1/c2 bits + flag via atomics. All blocks spin on the flag only at the
// epilogue (~flag is set long before most blocks get there).
__global__ __launch_bounds__(256, 2) void jmmd_fused(
    const uint8_t* __restrict__ t1f8, const uint8_t* __restrict__ t2f8,
    const float* __restrict__ sq1, const float* __restrict__ sq2,
    float* __restrict__ s1v, float* __restrict__ s2v,
    unsigned* __restrict__ ctrl, float* __restrict__ out) {
    __shared__ alignas(16) uint8_t smem[4][16384];   // A0,B0,A1,B1 — 64 KiB
    int tid = threadIdx.x;
    int bid = blockIdx.x;

    // ---- phase 0: colsum stripe (blocks 0..383 only) ----
    if (bid < 384) {
        int which = bid >= 256;
        int local = which ? bid - 256 : bid;
        int d = which ? D2 : D1;
        int colchunks = d >> 10;
        int cb = local % colchunks, rb = local / colchunks;
        const uint8_t* base = which ? t2f8 : t1f8;
        float* s = which ? s2v : s1v;
        int col = (cb << 10) + tid * 4;
        const uint8_t* p = base + (size_t)(rb * 64) * d + col;
        float a0 = 0.f, a1 = 0.f, a2 = 0.f, a3 = 0.f;
#pragma unroll 4
        for (int r = 0; r < 64; ++r) {
            uchar4 u = *(const uchar4*)(p + (size_t)r * d);
            a0 += fp8dec(u.x); a1 += fp8dec(u.y); a2 += fp8dec(u.z); a3 += fp8dec(u.w);
        }
        atomicAdd(&s[col], a0); atomicAdd(&s[col + 1], a1);
        atomicAdd(&s[col + 2], a2); atomicAdd(&s[col + 3], a3);
        __threadfence();
        __syncthreads();
        unsigned* rkp = (unsigned*)(smem[0] + 64);
        if (tid == 0) *rkp = atomicAdd(&ctrl[0], 1u);
        __syncthreads();
        unsigned rk = *rkp;
        __syncthreads();
        if (rk == 383u) {
            // ---- finalize (identical math to the old finalize_kernel) ----
            float a1_ = 0.f, a2_ = 0.f, q1_ = 0.f, q2_ = 0.f;
            for (int i = tid; i < 4096; i += 256) {
                float v = __uint_as_float(atomicOr((unsigned*)&s1v[i], 0u));
                a1_ += v * v; q1_ += sq1[i]; q2_ += sq2[i];
            }
            for (int i = tid; i < 2048; i += 256) {
                float v = __uint_as_float(atomicOr((unsigned*)&s2v[i], 0u));
                a2_ += v * v;
            }
            for (int o = 32; o; o >>= 1) {
                a1_ += __shfl_down(a1_, o); a2_ += __shfl_down(a2_, o);
                q1_ += __shfl_down(q1_, o); q2_ += __shfl_down(q2_, o);
            }
            float* fsh = (float*)smem[0];
            int lane = tid & 63, w = tid >> 6;
            if (lane == 0) { fsh[0 * 4 + w] = a1_; fsh[1 * 4 + w] = a2_; fsh[2 * 4 + w] = q1_; fsh[3 * 4 + w] = q2_; }
            __syncthreads();
            if (tid == 0) {
                double ss1 = (double)fsh[0] + fsh[1] + fsh[2] + fsh[3];
                double ss2 = (double)fsh[4] + fsh[5] + fsh[6] + fsh[7];
                double t1 = (double)fsh[8] + fsh[9] + fsh[10] + fsh[11];
                double t2 = (double)fsh[12] + fsh[13] + fsh[14] + fsh[15];
                double S1 = 2.0 * (double)NTOT * t1 - 2.0 * ss1;
                double S2 = 2.0 * (double)NTOT * t2 - 2.0 * ss2;
                const double L2E = 1.4426950408889634;
                double nn = (double)NTOT * (double)(NTOT - 1);
                atomicExch(&ctrl[2], __float_as_uint((float)(nn * L2E / (4.0 * S1))));
                atomicExch(&ctrl[3], __float_as_uint((float)(nn * L2E / (4.0 * S2))));
                __threadfence();
                atomicExch(&ctrl[1], 1u);
            }
            __syncthreads();
        }
    }

    // ---- phase 1: dual GEMM (R2-validated core) ----
    int ti = 0, r = bid;
    while (r >= TT - ti) { r -= TT - ti; ++ti; }
    int tj = ti + r;
    int i0 = ti * 128, j0 = tj * 128;
    int lane = tid & 63, wv = tid >> 6;
    int wm = wv >> 1, wn = wv & 1, lm = lane & 15, quad = lane >> 4;
    f32x4 acc1[4][4] = {};
    f32x4 acc2[4][4] = {};
    gemm_mx_pipe(t1f8 + (size_t)i0 * D1, t1f8 + (size_t)j0 * D1, D1,
                 smem[0], smem[1], smem[2], smem[3], acc1, wv, lane, wm, wn, lm, quad);
    asm volatile("s_waitcnt vmcnt(0)\n\ts_barrier" ::: "memory");
    gemm_mx_pipe(t2f8 + (size_t)i0 * D2, t2f8 + (size_t)j0 * D2, D2,
                 smem[0], smem[1], smem[2], smem[3], acc2, wv, lane, wm, wn, lm, quad);
    // drain GEMM2's dummy tail prefetch before reusing smem as scratch
    asm volatile("s_waitcnt vmcnt(0)" ::: "memory");
    __syncthreads();

    // ---- phase 2: wait for cv, then kernel epilogue ----
    float* cvp = (float*)smem[1];
    if (tid == 0) {
        while (atomicOr(&ctrl[1], 0u) == 0u) __builtin_amdgcn_s_sleep(8);
        cvp[0] = __uint_as_float(atomicOr(&ctrl[2], 0u));
        cvp[1] = __uint_as_float(atomicOr(&ctrl[3], 0u));
    }
    __syncthreads();
    float c1 = cvp[0], c2 = cvp[1];
    float local = 0.f;
    bool diag = (ti == tj);
#pragma unroll
    for (int mi = 0; mi < 4; ++mi) {
        int rbase = wm * 64 + mi * 16 + quad * 4;
#pragma unroll
        for (int ni = 0; ni < 4; ++ni) {
            int col = wn * 64 + ni * 16 + lm;
            float sb1 = sq1[j0 + col], sb2 = sq2[j0 + col];
#pragma unroll
            for (int rr = 0; rr < 4; ++rr) {
                int row = rbase + rr;
                float l2a = fmaxf(sq1[i0 + row] + sb1 - 2.f * acc1[mi][ni][rr], 0.f);
                float l2b = fmaxf(sq2[i0 + row] + sb2 - 2.f * acc2[mi][ni][rr], 0.f);
                float t1 = __builtin_amdgcn_exp2f(-l2a * c1);
                float k1 = t1; float u1 = t1 * t1; k1 += u1; u1 *= u1; k1 += u1; u1 *= u1; k1 += u1; u1 *= u1; k1 += u1;
                float t2 = __builtin_amdgcn_exp2f(-l2b * c2);
                float k2 = t2; float u2 = t2 * t2; k2 += u2; u2 *= u2; k2 += u2; u2 *= u2; k2 += u2; u2 *= u2; k2 += u2;
                float v = k1 * k2;
                if (diag && (row == col)) v = 0.f;
                local += v;
            }
        }
    }
    for (int o = 32; o; o >>= 1) local += __shfl_down(local, o);
    float* redp = (float*)smem[0];   // buffers dead past this point
    if (lane == 0) redp[wv] = local;
    __syncthreads();
    if (tid == 0) {
        bool same = (i0 < BHALF) == (j0 < BHALF);
        float w = same ? (1.0f / ((float)BHALF * (float)(BHALF - 1)))
                       : (-1.0f / ((float)BHALF * (float)BHALF));
        if (!diag) w *= 2.f;
        atomicAdd(out, (redp[0] + redp[1] + redp[2] + redp[3]) * w);
    }
}

extern "C" void kernel_launch(void* const* d_in, const int* in_sizes, int n_in,
                              void* d_out, int out_size, void* d_ws, size_t ws_size,
                              hipStream_t stream) {
    const float* z1s = (const float*)d_in[0];
    const float* z1t = (const float*)d_in[1];
    const float* z2s = (const float*)d_in[2];
    const float* z2t = (const float*)d_in[3];
    float* out = (float*)d_out;

    float* ws = (float*)d_ws;
    float* sq1 = ws;              // 4096
    float* sq2 = ws + 4096;       // 4096
    float* s1  = ws + 8192;       // 4096
    float* s2  = ws + 12288;      // 2048
    unsigned* ctrl = (unsigned*)(ws + 14336);          // [0]=done [1]=flag [2]=c1 [3]=c2
    uint8_t* t1f8 = (uint8_t*)(ws + 14344);            // 16B-aligned
    uint8_t* t2f8 = t1f8 + (size_t)NTOT * D1;

    prep_kernel<<<8192, 256, 0, stream>>>(z1s, z1t, z2s, z2t, sq1, sq2, t1f8, t2f8, s1, s2, ctrl, out);
    jmmd_fused<<<NTILES, 256, 0, stream>>>(t1f8, t2f8, sq1, sq2, s1, s2, ctrl, out);
}

// Round 5
// 284.402 us; speedup vs baseline: 1.0428x; 1.0428x over previous
//
#include <hip/hip_runtime.h>
#include <cstdint>

#define NTOT 4096   // 2b rows
#define BHALF 2048  // b
#define D1 4096
#define D2 2048
#define TT 32       // 4096/128 tiles per dim
#define NTILES 528  // TT*(TT+1)/2

typedef __attribute__((ext_vector_type(4))) float f32x4;
typedef __attribute__((ext_vector_type(4))) int i32x4;
typedef __attribute__((ext_vector_type(8))) int i32x8;

// async 16B global->LDS DMA (wave-uniform LDS base + lane*16 scatter)
__device__ __forceinline__ void glds16(const uint8_t* g, uint8_t* l) {
    __builtin_amdgcn_global_load_lds(
        (const __attribute__((address_space(1))) void*)(uintptr_t)g,
        (__attribute__((address_space(3))) void*)(uint32_t)(uintptr_t)l,
        16, 0, 0);
}

// raw LDS b128 read, opaque to the compiler's waitcnt insertion
__device__ __forceinline__ i32x4 ldsr(uint32_t addr) {
    i32x4 r;
    asm volatile("ds_read_b128 %0, %1" : "=v"(r) : "v"(addr));
    return r;
}

// e4m3fn decode (for colsum only; data never near NaN/448)
__device__ __forceinline__ float fp8dec(unsigned b) {
    unsigned e = (b >> 3) & 15u, m = b & 7u;
    float v = e ? __uint_as_float(((e + 120u) << 23) | (m << 20))
                : (float)m * 0.001953125f;   // subnormal: m * 2^-9
    return (b & 128u) ? -v : v;
}

__device__ __forceinline__ int cvt2fp8(float4 v) {
    int w = __builtin_amdgcn_cvt_pk_fp8_f32(v.x, v.y, 0, 0);
    return __builtin_amdgcn_cvt_pk_fp8_f32(v.z, v.w, w, 1);
}

// ---------------- prep: per-row sumsq (fp32) + fp8 e4m3 convert ----------------
// R5: compile-time d per branch so ALL row loads issue before any use (4 float4
// in flight for D1 rows, 2 for D2) instead of one-load-wait-cvt-store per loop
// iteration (runtime-d loop = one serial HBM latency per iteration — the theory
// for prep's 5x-off-roofline 110 µs). Per-thread accumulation order of `a` is
// IDENTICAL to the validated form (iter0 v0,v1 then iter1 v0,v1).
__global__ __launch_bounds__(256, 4) void prep_kernel(
        const float* __restrict__ z1s, const float* __restrict__ z1t,
        const float* __restrict__ z2s, const float* __restrict__ z2t,
        float* __restrict__ sq1, float* __restrict__ sq2,
        uint8_t* __restrict__ t1f8, uint8_t* __restrict__ t2f8,
        float* __restrict__ s1, float* __restrict__ s2,
        unsigned* __restrict__ ctrl, float* __restrict__ out) {
    int bid = blockIdx.x;
    int tid = threadIdx.x;
    if (bid == 0) { for (int i = tid; i < 4096; i += 256) s1[i] = 0.f; }
    if (bid == 1) { for (int i = tid; i < 2048; i += 256) s2[i] = 0.f; }
    if (bid == 2) {
        if (tid == 0) ctrl[0] = 0u;                     // colsum completion counter
        if (tid == 1) out[0] = 2.0f / (float)(BHALF - 1);
    }
    int which = bid >> 12;
    int row = bid & 4095;
    float a = 0.f;
    if (which == 0) {
        const float* src = (row < BHALF) ? z1s + (size_t)row * D1
                                         : z1t + (size_t)(row - BHALF) * D1;
        uint8_t* dst = t1f8 + (size_t)row * D1;
        const float4* s4 = (const float4*)src;
        // iter i=tid -> s4[2*tid], s4[2*tid+1]; iter i=tid+256 -> s4[2*tid+512], [513]
        float4 p0 = s4[2 * tid], p1 = s4[2 * tid + 1];
        float4 p2 = s4[2 * tid + 512], p3 = s4[2 * tid + 513];
        a += p0.x * p0.x + p0.y * p0.y + p0.z * p0.z + p0.w * p0.w;
        a += p1.x * p1.x + p1.y * p1.y + p1.z * p1.z + p1.w * p1.w;
        a += p2.x * p2.x + p2.y * p2.y + p2.z * p2.z + p2.w * p2.w;
        a += p3.x * p3.x + p3.y * p3.y + p3.z * p3.z + p3.w * p3.w;
        ((uint2*)dst)[tid]       = uint2{(unsigned)cvt2fp8(p0), (unsigned)cvt2fp8(p1)};
        ((uint2*)dst)[tid + 256] = uint2{(unsigned)cvt2fp8(p2), (unsigned)cvt2fp8(p3)};
    } else {
        const float* src = (row < BHALF) ? z2s + (size_t)row * D2
                                         : z2t + (size_t)(row - BHALF) * D2;
        uint8_t* dst = t2f8 + (size_t)row * D2;
        const float4* s4 = (const float4*)src;
        float4 p0 = s4[2 * tid], p1 = s4[2 * tid + 1];
        a += p0.x * p0.x + p0.y * p0.y + p0.z * p0.z + p0.w * p0.w;
        a += p1.x * p1.x + p1.y * p1.y + p1.z * p1.z + p1.w * p1.w;
        ((uint2*)dst)[tid] = uint2{(unsigned)cvt2fp8(p0), (unsigned)cvt2fp8(p1)};
    }
    for (int o = 32; o; o >>= 1) a += __shfl_down(a, o);
    __shared__ float sh[4];
    int lane = tid & 63, w = tid >> 6;
    if (lane == 0) sh[w] = a;
    __syncthreads();
    if (tid == 0) (which ? sq2 : sq1)[row] = sh[0] + sh[1] + sh[2] + sh[3];
}

// ---------------- column sums + folded finalize (last-finisher block) ----------------
// Stripe mapping/partials/atomic targets identical to the R2-validated 384-block
// colsum. The 384th completer block runs the finalize math (R4-validated pattern:
// s1/s2 read via bit-exact device-scope atomicOr loads; results stored plain —
// visibility to the later jmmd dispatch is guaranteed by the kernel boundary).
__global__ void colsum_fin_kernel(const uint8_t* __restrict__ t1f8,
                                  const uint8_t* __restrict__ t2f8,
                                  float* __restrict__ s1, float* __restrict__ s2,
                                  const float* __restrict__ sq1, const float* __restrict__ sq2,
                                  unsigned* __restrict__ ctrl, float* __restrict__ acc) {
    int bid = blockIdx.x;
    int tid = threadIdx.x;
    int which = bid >= 256;
    int local = which ? bid - 256 : bid;
    int d = which ? D2 : D1;
    int colchunks = d >> 10;
    int cb = local % colchunks, rb = local / colchunks;
    const uint8_t* base = which ? t2f8 : t1f8;
    float* s = which ? s2 : s1;
    int col = (cb << 10) + tid * 4;
    const uint8_t* p = base + (size_t)(rb * 64) * d + col;
    float a0 = 0.f, a1 = 0.f, a2 = 0.f, a3 = 0.f;
#pragma unroll 4
    for (int r = 0; r < 64; ++r) {
        uchar4 u = *(const uchar4*)(p + (size_t)r * d);
        a0 += fp8dec(u.x); a1 += fp8dec(u.y); a2 += fp8dec(u.z); a3 += fp8dec(u.w);
    }
    atomicAdd(&s[col], a0); atomicAdd(&s[col + 1], a1);
    atomicAdd(&s[col + 2], a2); atomicAdd(&s[col + 3], a3);
    __threadfence();
    __syncthreads();
    __shared__ unsigned rk_sh;
    __shared__ float fsh[16];
    if (tid == 0) rk_sh = atomicAdd(&ctrl[0], 1u);
    __syncthreads();
    if (rk_sh != 383u) return;
    // ---- finalize (identical math to the validated finalize_kernel) ----
    float a1_ = 0.f, a2_ = 0.f, q1_ = 0.f, q2_ = 0.f;
    for (int i = tid; i < 4096; i += 256) {
        float v = __uint_as_float(atomicOr((unsigned*)&s1[i], 0u));
        a1_ += v * v; q1_ += sq1[i]; q2_ += sq2[i];
    }
    for (int i = tid; i < 2048; i += 256) {
        float v = __uint_as_float(atomicOr((unsigned*)&s2[i], 0u));
        a2_ += v * v;
    }
    for (int o = 32; o; o >>= 1) {
        a1_ += __shfl_down(a1_, o); a2_ += __shfl_down(a2_, o);
        q1_ += __shfl_down(q1_, o); q2_ += __shfl_down(q2_, o);
    }
    int lane = tid & 63, w = tid >> 6;
    if (lane == 0) { fsh[0 + w] = a1_; fsh[4 + w] = a2_; fsh[8 + w] = q1_; fsh[12 + w] = q2_; }
    __syncthreads();
    if (tid == 0) {
        double ss1 = (double)fsh[0] + fsh[1] + fsh[2] + fsh[3];
        double ss2 = (double)fsh[4] + fsh[5] + fsh[6] + fsh[7];
        double t1 = (double)fsh[8] + fsh[9] + fsh[10] + fsh[11];
        double t2 = (double)fsh[12] + fsh[13] + fsh[14] + fsh[15];
        double S1 = 2.0 * (double)NTOT * t1 - 2.0 * ss1;
        double S2 = 2.0 * (double)NTOT * t2 - 2.0 * ss2;
        const double L2E = 1.4426950408889634;
        double nn = (double)NTOT * (double)(NTOT - 1);
        acc[2] = (float)(nn * L2E / (4.0 * S1));
        acc[3] = (float)(nn * L2E / (4.0 * S2));
    }
}

// ---------------- pipelined MX-fp8 GEMM K-loop (R2-validated 4-wave form) ----------
__device__ __forceinline__ void gemm_mx_pipe(const uint8_t* __restrict__ ga,
                                             const uint8_t* __restrict__ gb,
                                             int d,
                                             uint8_t* A0, uint8_t* B0,
                                             uint8_t* A1, uint8_t* B1,
                                             f32x4 (&acc)[4][4], int wv, int lane,
                                             int wm, int wn, int lm, int quad) {
    int nsteps = d >> 7;
    int rsub = lane >> 3;
    int ql = (lane & 7) ^ rsub;          // swizzled source chunk
    const uint8_t* pa = ga + (size_t)(wv * 32 + rsub) * d + ql * 16;
    const uint8_t* pb = gb + (size_t)(wv * 32 + rsub) * d + ql * 16;
    uint8_t* dA[2] = { A0 + wv * 4096, A1 + wv * 4096 };
    uint8_t* dB[2] = { B0 + wv * 4096, B1 + wv * 4096 };
    uint32_t baseA[2] = { (uint32_t)(uintptr_t)A0, (uint32_t)(uintptr_t)A1 };
    uint32_t baseB[2] = { (uint32_t)(uintptr_t)B0, (uint32_t)(uintptr_t)B1 };
    int s0 = ((2 * quad) ^ (lm & 7)) * 16;
    int s1 = ((2 * quad + 1) ^ (lm & 7)) * 16;
    uint32_t offA[4], offB[4];
#pragma unroll
    for (int i = 0; i < 4; ++i) {
        offA[i] = (uint32_t)((wm * 64 + i * 16 + lm) * 128);
        offB[i] = (uint32_t)((wn * 64 + i * 16 + lm) * 128);
    }
    // prime buffer 0 (k=0)
#pragma unroll
    for (int i = 0; i < 4; ++i) {
        glds16(pa + (size_t)i * 8 * d, dA[0] + i * 1024);
        glds16(pb + (size_t)i * 8 * d, dB[0] + i * 1024);
    }
    for (int k = 0; k < nsteps; ++k) {
        int cur = k & 1, nxt = cur ^ 1;
        size_t koff = (size_t)((k + 1 < nsteps) ? (k + 1) : 0) << 7;
#pragma unroll
        for (int i = 0; i < 4; ++i) {
            glds16(pa + koff + (size_t)i * 8 * d, dA[nxt] + i * 1024);
            glds16(pb + koff + (size_t)i * 8 * d, dB[nxt] + i * 1024);
        }
        asm volatile("s_waitcnt vmcnt(8)\n\ts_barrier" ::: "memory");
        i32x4 b00 = ldsr(baseB[cur] + offB[0] + s0), b01 = ldsr(baseB[cur] + offB[0] + s1);
        i32x4 b10 = ldsr(baseB[cur] + offB[1] + s0), b11 = ldsr(baseB[cur] + offB[1] + s1);
        i32x4 a00 = ldsr(baseA[cur] + offA[0] + s0), a01 = ldsr(baseA[cur] + offA[0] + s1);
        i32x4 a10 = ldsr(baseA[cur] + offA[1] + s0), a11 = ldsr(baseA[cur] + offA[1] + s1);
        i32x4 b20 = ldsr(baseB[cur] + offB[2] + s0), b21 = ldsr(baseB[cur] + offB[2] + s1);
        i32x4 b30 = ldsr(baseB[cur] + offB[3] + s0), b31 = ldsr(baseB[cur] + offB[3] + s1);
        i32x4 a20 = ldsr(baseA[cur] + offA[2] + s0), a21 = ldsr(baseA[cur] + offA[2] + s1);
        i32x4 a30 = ldsr(baseA[cur] + offA[3] + s0), a31 = ldsr(baseA[cur] + offA[3] + s1);
        union F { i32x4 h[2]; i32x8 v; };
        F ua0, ua1, ua2, ua3, ub0, ub1, ub2, ub3;
        // ---- cluster 0: needs first 8 reads (8 in flight) ----
        asm volatile("s_waitcnt lgkmcnt(8)"
                     : "+v"(b00), "+v"(b01), "+v"(b10), "+v"(b11),
                       "+v"(a00), "+v"(a01), "+v"(a10), "+v"(a11));
        __builtin_amdgcn_sched_barrier(0);
        ub0.h[0] = b00; ub0.h[1] = b01; ub1.h[0] = b10; ub1.h[1] = b11;
        ua0.h[0] = a00; ua0.h[1] = a01; ua1.h[0] = a10; ua1.h[1] = a11;
        __builtin_amdgcn_s_setprio(1);
        acc[0][0] = __builtin_amdgcn_mfma_scale_f32_16x16x128_f8f6f4(ua0.v, ub0.v, acc[0][0], 0, 0, 0, 0x7F7F7F7F, 0, 0x7F7F7F7F);
        acc[0][1] = __builtin_amdgcn_mfma_scale_f32_16x16x128_f8f6f4(ua0.v, ub1.v, acc[0][1], 0, 0, 0, 0x7F7F7F7F, 0, 0x7F7F7F7F);
        acc[1][0] = __builtin_amdgcn_mfma_scale_f32_16x16x128_f8f6f4(ua1.v, ub0.v, acc[1][0], 0, 0, 0, 0x7F7F7F7F, 0, 0x7F7F7F7F);
        acc[1][1] = __builtin_amdgcn_mfma_scale_f32_16x16x128_f8f6f4(ua1.v, ub1.v, acc[1][1], 0, 0, 0, 0x7F7F7F7F, 0, 0x7F7F7F7F);
        __builtin_amdgcn_s_setprio(0);
        // ---- cluster 1: + B frag 2,3 ----
        asm volatile("s_waitcnt lgkmcnt(4)"
                     : "+v"(b20), "+v"(b21), "+v"(b30), "+v"(b31));
        __builtin_amdgcn_sched_barrier(0);
        ub2.h[0] = b20; ub2.h[1] = b21; ub3.h[0] = b30; ub3.h[1] = b31;
        __builtin_amdgcn_s_setprio(1);
        acc[0][2] = __builtin_amdgcn_mfma_scale_f32_16x16x128_f8f6f4(ua0.v, ub2.v, acc[0][2], 0, 0, 0, 0x7F7F7F7F, 0, 0x7F7F7F7F);
        acc[0][3] = __builtin_amdgcn_mfma_scale_f32_16x16x128_f8f6f4(ua0.v, ub3.v, acc[0][3], 0, 0, 0, 0x7F7F7F7F, 0, 0x7F7F7F7F);
        acc[1][2] = __builtin_amdgcn_mfma_scale_f32_16x16x128_f8f6f4(ua1.v, ub2.v, acc[1][2], 0, 0, 0, 0x7F7F7F7F, 0, 0x7F7F7F7F);
        acc[1][3] = __builtin_amdgcn_mfma_scale_f32_16x16x128_f8f6f4(ua1.v, ub3.v, acc[1][3], 0, 0, 0, 0x7F7F7F7F, 0, 0x7F7F7F7F);
        __builtin_amdgcn_s_setprio(0);
        // ---- all reads landed: release buffer (WAR barrier); clusters 2/3 run
        // register-only in the barrier shadow ----
        asm volatile("s_waitcnt lgkmcnt(0)"
                     : "+v"(a20), "+v"(a21), "+v"(a30), "+v"(a31));
        __builtin_amdgcn_sched_barrier(0);
        asm volatile("s_barrier" ::: "memory");
        __builtin_amdgcn_sched_barrier(0);
        ua2.h[0] = a20; ua2.h[1] = a21; ua3.h[0] = a30; ua3.h[1] = a31;
        __builtin_amdgcn_s_setprio(1);
        acc[2][0] = __builtin_amdgcn_mfma_scale_f32_16x16x128_f8f6f4(ua2.v, ub0.v, acc[2][0], 0, 0, 0, 0x7F7F7F7F, 0, 0x7F7F7F7F);
        acc[2][1] = __builtin_amdgcn_mfma_scale_f32_16x16x128_f8f6f4(ua2.v, ub1.v, acc[2][1], 0, 0, 0, 0x7F7F7F7F, 0, 0x7F7F7F7F);
        acc[2][2] = __builtin_amdgcn_mfma_scale_f32_16x16x128_f8f6f4(ua2.v, ub2.v, acc[2][2], 0, 0, 0, 0x7F7F7F7F, 0, 0x7F7F7F7F);
        acc[2][3] = __builtin_amdgcn_mfma_scale_f32_16x16x128_f8f6f4(ua2.v, ub3.v, acc[2][3], 0, 0, 0, 0x7F7F7F7F, 0, 0x7F7F7F7F);
        acc[3][0] = __builtin_amdgcn_mfma_scale_f32_16x16x128_f8f6f4(ua3.v, ub0.v, acc[3][0], 0, 0, 0, 0x7F7F7F7F, 0, 0x7F7F7F7F);
        acc[3][1] = __builtin_amdgcn_mfma_scale_f32_16x16x128_f8f6f4(ua3.v, ub1.v, acc[3][1], 0, 0, 0, 0x7F7F7F7F, 0, 0x7F7F7F7F);
        acc[3][2] = __builtin_amdgcn_mfma_scale_f32_16x16x128_f8f6f4(ua3.v, ub2.v, acc[3][2], 0, 0, 0, 0x7F7F7F7F, 0, 0x7F7F7F7F);
        acc[3][3] = __builtin_amdgcn_mfma_scale_f32_16x16x128_f8f6f4(ua3.v, ub3.v, acc[3][3], 0, 0, 0, 0x7F7F7F7F, 0, 0x7F7F7F7F);
        __builtin_amdgcn_s_setprio(0);
    }
}

// ---------------- fused dual-GEMM + kernel epilogue (exact R2-validated form) ----
__global__ __launch_bounds__(256, 2) void jmmd_fused(
    const uint8_t* __restrict__ t1f8, const uint8_t* __restrict__ t2f8,
    const float* __restrict__ sq1, const float* __restrict__ sq2,
    const float* __restrict__ cv, float* __restrict__ out) {
    __shared__ alignas(16) uint8_t smem[4][16384];   // A0,B0,A1,B1 — exactly 64 KiB
    int tid = threadIdx.x;
    int ti = 0, r = blockIdx.x;
    while (r >= TT - ti) { r -= TT - ti; ++ti; }
    int tj = ti + r;
    int i0 = ti * 128, j0 = tj * 128;
    int lane = tid & 63, wv = tid >> 6;
    int wm = wv >> 1, wn = wv & 1, lm = lane & 15, quad = lane >> 4;
    f32x4 acc1[4][4] = {};
    f32x4 acc2[4][4] = {};
    gemm_mx_pipe(t1f8 + (size_t)i0 * D1, t1f8 + (size_t)j0 * D1, D1,
                 smem[0], smem[1], smem[2], smem[3], acc1, wv, lane, wm, wn, lm, quad);
    asm volatile("s_waitcnt vmcnt(0)\n\ts_barrier" ::: "memory");
    gemm_mx_pipe(t2f8 + (size_t)i0 * D2, t2f8 + (size_t)j0 * D2, D2,
                 smem[0], smem[1], smem[2], smem[3], acc2, wv, lane, wm, wn, lm, quad);
    // drain GEMM2's dummy tail prefetch before reusing smem[0] as scratch
    asm volatile("s_waitcnt vmcnt(0)" ::: "memory");
    __syncthreads();
    float c1 = cv[0], c2 = cv[1];
    float local = 0.f;
    bool diag = (ti == tj);
#pragma unroll
    for (int mi = 0; mi < 4; ++mi) {
        int rbase = wm * 64 + mi * 16 + quad * 4;
#pragma unroll
        for (int ni = 0; ni < 4; ++ni) {
            int col = wn * 64 + ni * 16 + lm;
            float sb1 = sq1[j0 + col], sb2 = sq2[j0 + col];
#pragma unroll
            for (int rr = 0; rr < 4; ++rr) {
                int row = rbase + rr;
                float l2a = fmaxf(sq1[i0 + row] + sb1 - 2.f * acc1[mi][ni][rr], 0.f);
                float l2b = fmaxf(sq2[i0 + row] + sb2 - 2.f * acc2[mi][ni][rr], 0.f);
                float t1 = __builtin_amdgcn_exp2f(-l2a * c1);
                float k1 = t1; float u1 = t1 * t1; k1 += u1; u1 *= u1; k1 += u1; u1 *= u1; k1 += u1; u1 *= u1; k1 += u1;
                float t2 = __builtin_amdgcn_exp2f(-l2b * c2);
                float k2 = t2; float u2 = t2 * t2; k2 += u2; u2 *= u2; k2 += u2; u2 *= u2; k2 += u2; u2 *= u2; k2 += u2;
                float v = k1 * k2;
                if (diag && (row == col)) v = 0.f;
                local += v;
            }
        }
    }
    for (int o = 32; o; o >>= 1) local += __shfl_down(local, o);
    float* redp = (float*)smem[0];   // buffers dead past this point
    if (lane == 0) redp[wv] = local;
    __syncthreads();
    if (tid == 0) {
        bool same = (i0 < BHALF) == (j0 < BHALF);
        float w = same ? (1.0f / ((float)BHALF * (float)(BHALF - 1)))
                       : (-1.0f / ((float)BHALF * (float)BHALF));
        if (!diag) w *= 2.f;
        atomicAdd(out, (redp[0] + redp[1] + redp[2] + redp[3]) * w);
    }
}

extern "C" void kernel_launch(void* const* d_in, const int* in_sizes, int n_in,
                              void* d_out, int out_size, void* d_ws, size_t ws_size,
                              hipStream_t stream) {
    const float* z1s = (const float*)d_in[0];
    const float* z1t = (const float*)d_in[1];
    const float* z2s = (const float*)d_in[2];
    const float* z2t = (const float*)d_in[3];
    float* out = (float*)d_out;

    float* ws = (float*)d_ws;
    float* sq1 = ws;              // 4096
    float* sq2 = ws + 4096;       // 4096
    float* s1  = ws + 8192;       // 4096
    float* s2  = ws + 12288;      // 2048
    float* acc = ws + 14336;      // [2]=c1 [3]=c2
    unsigned* ctrl = (unsigned*)(ws + 14340);          // [0]=colsum done counter
    uint8_t* t1f8 = (uint8_t*)(ws + 14344);            // 16B-aligned
    uint8_t* t2f8 = t1f8 + (size_t)NTOT * D1;

    prep_kernel<<<8192, 256, 0, stream>>>(z1s, z1t, z2s, z2t, sq1, sq2, t1f8, t2f8, s1, s2, ctrl, out);
    colsum_fin_kernel<<<384, 256, 0, stream>>>(t1f8, t2f8, s1, s2, sq1, sq2, ctrl, acc);
    jmmd_fused<<<NTILES, 256, 0, stream>>>(t1f8, t2f8, sq1, sq2, acc + 2, out);
}